// Round 10
// baseline (324.658 us; speedup 1.0000x reference)
//
#include <hip/hip_runtime.h>
#include <math.h>

// Problem constants (fixed by reference)
#define B_TOT   256
#define N_TOT   2304
#define IN_DIM  8
#define NC      10      // NUM_CLASSES
#define OD      16      // OUT_DIM
#define CD      160     // NC*OD
#define RBIAS   0.1f

// Tiling: wave-per-class layout. Block = 10 waves (c=0..9) × 64 lanes (b).
#define BTILE    64                      // b per block (= wave lanes)
#define NS       192                     // n-slices (grid.y); grid = 4*192 = 768 = 3 blk/CU
#define NPB      (N_TOT / NS)            // 12 n per block
#define NTHREADS 640                     // 10 waves
#define XR       (NPB * IN_DIM + 4)      // 100: x row stride
#define LB       72                      // logit board row stride
#define NF4      (B_TOT * CD / 4)        // 10240 float4 per partial slab
#define YGRP     8                       // reduce stage-A groups
#define YPER     (NS / YGRP)             // 24 slabs per group
#define GCHUNKS  (NF4 / 256)             // 40 g-chunks in the reduce grid

// ===== R7's proven routing round (52us, VGPR=32, 0 bank conflicts) — unchanged =====
// Wave c, lane b. Thread owns u[16] for (b0+b, class c). W[n,i,c*16..+16) is
// wave-uniform -> scalar loads (SGPR operand); W never touches LDS/VGPRs.
// FIRST=1: cw uniform -> acc += u, no logits/barriers; 0.1 folded in reduce.
template <int FIRST>
__global__ __launch_bounds__(NTHREADS) void routing_round(
    const float* __restrict__ x,      // [B, N, 8]
    const float* __restrict__ W,      // [N, 8, 160]
    const float* __restrict__ S_acc,  // [B, 160]
    float* __restrict__ part)         // [NS, B, 160]
{
    __shared__ float sh_x[BTILE * XR];            // 25.6 KB
    __shared__ float sh_lg[2][NC * LB];           // 5.8 KB

    const int tid = threadIdx.x;
    const int b0  = blockIdx.x * BTILE;
    const int n0  = blockIdx.y * NPB;
    const int b   = tid & 63;
    const int cu  = __builtin_amdgcn_readfirstlane(tid >> 6);

    // ---- stage x tile: [64 b][96 floats], coalesced float4
    {
        const int XT4 = BTILE * (NPB * IN_DIM / 4);   // 1536
        for (int k = tid; k < XT4; k += NTHREADS) {
            int bb   = k / (NPB * 2);
            int off4 = k - bb * (NPB * 2);
            float4 v = *(const float4*)(x + ((size_t)(b0 + bb) * N_TOT + n0) * IN_DIM + off4 * 4);
            *(float4*)(&sh_x[bb * XR + off4 * 4]) = v;
        }
    }

    // ---- S fragment: all 16 d for (b, c)
    float S[OD];
    if (!FIRST) {
        const float4* sp = (const float4*)(S_acc + (size_t)(b0 + b) * CD + cu * OD);
        #pragma unroll
        for (int q = 0; q < 4; q++) ((float4*)S)[q] = sp[q];
    }

    float acc[OD];
    #pragma unroll
    for (int d = 0; d < OD; d++) acc[d] = 0.f;

    __syncthreads();   // sh_x ready

    const float* Wc = W + cu * OD;    // wave-uniform base

    for (int nn = 0; nn < NPB; nn++) {
        float xf[IN_DIM];
        {
            const float4* xp = (const float4*)(&sh_x[b * XR + nn * IN_DIM]);
            ((float4*)xf)[0] = xp[0];
            ((float4*)xf)[1] = xp[1];
        }

        const float* Wn = Wc + (size_t)(n0 + nn) * (IN_DIM * CD);
        float u[OD];
        #pragma unroll
        for (int d = 0; d < OD; d++) u[d] = xf[0] * Wn[d];
        #pragma unroll
        for (int i = 1; i < IN_DIM; i++) {
            const float* Wi = Wn + i * CD;
            #pragma unroll
            for (int d = 0; d < OD; d++) u[d] = fmaf(xf[i], Wi[d], u[d]);
        }

        if (!FIRST) {
            const int cur = nn & 1;
            float lg = 0.f;
            #pragma unroll
            for (int d = 0; d < OD; d++) lg = fmaf(u[d], S[d], lg);
            sh_lg[cur][cu * LB + b] = lg;
            __syncthreads();

            float m = -1e30f;
            float row[NC];
            #pragma unroll
            for (int k = 0; k < NC; k++) {
                row[k] = sh_lg[cur][k * LB + b];
                m = fmaxf(m, row[k]);
            }
            float den = 0.f;
            #pragma unroll
            for (int k = 0; k < NC; k++) den += __expf(row[k] - m);
            float cw = __expf(lg - m) / den;

            #pragma unroll
            for (int d = 0; d < OD; d++) acc[d] = fmaf(cw, u[d], acc[d]);
        } else {
            #pragma unroll
            for (int d = 0; d < OD; d++) acc[d] += u[d];
        }
    }

    float* dst = part + ((size_t)blockIdx.y * B_TOT + (b0 + b)) * CD + cu * OD;
    #pragma unroll
    for (int q = 0; q < 4; q++)
        ((float4*)dst)[q] = ((float4*)acc)[q];
}

// ===== Fused fan-in reduce: stage A (8 blocks per g-chunk sum 24 slabs each)
// + device-scope counter; the 8th finisher does stage B for its g-chunk:
// fold into S_acc (store on round 0 — no memset needed; add on round 1) or
// squash -> v_out (round 2). Release: threadfence before atomicAdd; acquire:
// threadfence after winning. No dispatch-order assumption (G16-safe).
__global__ __launch_bounds__(256) void reduce_fanin(
    const float* __restrict__ part,   // [NS, B, 160]
    float* __restrict__ p2,           // [YGRP, B, 160]
    float* __restrict__ S_acc,        // [B, 160]
    float* __restrict__ v_out,        // [B, 10, 16]
    unsigned int* __restrict__ cnt,   // [GCHUNKS] zeroed counters for this round
    float scale, int round)
{
    const int g = blockIdx.x * 256 + threadIdx.x;   // float4 index
    const int k = blockIdx.y;                        // y-group 0..7

    // ---- stage A
    const float4* p4 = (const float4*)part + (size_t)k * YPER * NF4 + g;
    float4 s = { 0.f, 0.f, 0.f, 0.f };
    #pragma unroll 4
    for (int yy = 0; yy < YPER; yy++) {
        float4 t = p4[(size_t)yy * NF4];
        s.x += t.x; s.y += t.y; s.z += t.z; s.w += t.w;
    }
    ((float4*)p2)[(size_t)k * NF4 + g] = s;

    // ---- fan-in: last of the 8 k-blocks for this g-chunk does stage B
    __threadfence();                 // release our p2 stores (device scope)
    __syncthreads();                 // all threads' stores issued before count
    __shared__ unsigned int sold;
    if (threadIdx.x == 0) sold = atomicAdd(&cnt[blockIdx.x], 1u);
    __syncthreads();
    if (sold != YGRP - 1) return;    // not the last finisher
    __threadfence();                 // acquire: other blocks' p2 stores visible

    float4 t = { 0.f, 0.f, 0.f, 0.f };
    #pragma unroll
    for (int kk = 0; kk < YGRP; kk++) {
        float4 q = ((const float4*)p2)[(size_t)kk * NF4 + g];
        t.x += q.x; t.y += q.y; t.z += q.z; t.w += q.w;
    }
    t.x = t.x * scale + RBIAS;
    t.y = t.y * scale + RBIAS;
    t.z = t.z * scale + RBIAS;
    t.w = t.w * scale + RBIAS;

    if (round == 0) {
        ((float4*)S_acc)[g] = t;                    // store: no S_acc memset
    } else if (round == 1) {
        float4 o = ((float4*)S_acc)[g];
        o.x += t.x; o.y += t.y; o.z += t.z; o.w += t.w;
        ((float4*)S_acc)[g] = o;
    } else {
        // squash over 16 d = 4 consecutive lanes (one (b,c) row)
        float ss = t.x * t.x + t.y * t.y + t.z * t.z + t.w * t.w;
        ss += __shfl_xor(ss, 1, 64);
        ss += __shfl_xor(ss, 2, 64);
        float norm = sqrtf(ss);
        float k2 = norm / (1.0f + ss);
        float4 v = { t.x * k2, t.y * k2, t.z * k2, t.w * k2 };
        ((float4*)v_out)[g] = v;
    }
}

extern "C" void kernel_launch(void* const* d_in, const int* in_sizes, int n_in,
                              void* d_out, int out_size, void* d_ws, size_t ws_size,
                              hipStream_t stream) {
    const float* x = (const float*)d_in[0];   // [256,2304,8]
    const float* W = (const float*)d_in[1];   // [2304,8,160]
    float* out = (float*)d_out;               // [256,10,16]

    // Workspace layout
    float* part  = (float*)d_ws;                            // NS * 40960  (~31.5 MB)
    float* p2    = part + (size_t)NS * B_TOT * CD;          // YGRP * 40960
    float* S_acc = p2 + (size_t)YGRP * B_TOT * CD;          // 40960
    unsigned int* cnt = (unsigned int*)(S_acc + (size_t)B_TOT * CD);  // 3*GCHUNKS

    hipMemsetAsync(cnt, 0, 3 * GCHUNKS * sizeof(unsigned int), stream);

    const dim3 rgrid(B_TOT / BTILE, NS);
    const dim3 fgrid(GCHUNKS, YGRP);

    // Round 0 (uniform cw; 0.1 folded into reduce scale)
    routing_round<1><<<rgrid, NTHREADS, 0, stream>>>(x, W, S_acc, part);
    reduce_fanin<<<fgrid, 256, 0, stream>>>(part, p2, S_acc, out, cnt, 0.1f, 0);

    // Round 1
    routing_round<0><<<rgrid, NTHREADS, 0, stream>>>(x, W, S_acc, part);
    reduce_fanin<<<fgrid, 256, 0, stream>>>(part, p2, S_acc, out, cnt + GCHUNKS, 1.0f, 1);

    // Round 2 (+final squash)
    routing_round<0><<<rgrid, NTHREADS, 0, stream>>>(x, W, S_acc, part);
    reduce_fanin<<<fgrid, 256, 0, stream>>>(part, p2, S_acc, out, cnt + 2 * GCHUNKS, 1.0f, 2);
}

// Round 11
// 224.211 us; speedup vs baseline: 1.4480x; 1.4480x over previous
//
#include <hip/hip_runtime.h>
#include <math.h>

// Problem constants (fixed by reference)
#define B_TOT   256
#define N_TOT   2304
#define IN_DIM  8
#define NC      10      // NUM_CLASSES
#define OD      16      // OUT_DIM
#define CD      160     // NC*OD
#define RBIAS   0.1f

// Tiling: wave-per-class layout. Block = 10 waves (c=0..9) × 64 lanes (b).
#define BTILE    64                      // b per block (= wave lanes)
#define NS       192                     // n-slices (grid.y); grid = 4*192 = 768 = 3 blk/CU
#define NPB      (N_TOT / NS)            // 12 n per block
#define NTHREADS 640                     // 10 waves
#define XR       (NPB * IN_DIM + 4)      // 100: x row stride
#define LB       72                      // logit board row stride
#define NF4      (B_TOT * CD / 4)        // 10240 float4 per partial slab
#define RSUB     4                       // reduce sub-groups per block
#define YSUB     (NS / RSUB)             // 48 slabs per sub-group

// ===== R7's proven routing round (51.2us, VGPR=32, 0 bank conflicts) — UNCHANGED =====
// Wave c, lane b. Thread owns u[16] for (b0+b, class c). W[n,i,c*16..+16) is
// wave-uniform -> scalar loads (SGPR operand); W never touches LDS/VGPRs.
// FIRST=1: cw uniform -> acc += u, no logits/barriers; 0.1 folded in reduce.
template <int FIRST>
__global__ __launch_bounds__(NTHREADS) void routing_round(
    const float* __restrict__ x,      // [B, N, 8]
    const float* __restrict__ W,      // [N, 8, 160]
    const float* __restrict__ S_acc,  // [B, 160]
    float* __restrict__ part)         // [NS, B, 160]
{
    __shared__ float sh_x[BTILE * XR];            // 25.6 KB
    __shared__ float sh_lg[2][NC * LB];           // 5.8 KB

    const int tid = threadIdx.x;
    const int b0  = blockIdx.x * BTILE;
    const int n0  = blockIdx.y * NPB;
    const int b   = tid & 63;
    const int cu  = __builtin_amdgcn_readfirstlane(tid >> 6);

    // ---- stage x tile: [64 b][96 floats], coalesced float4
    {
        const int XT4 = BTILE * (NPB * IN_DIM / 4);   // 1536
        for (int k = tid; k < XT4; k += NTHREADS) {
            int bb   = k / (NPB * 2);
            int off4 = k - bb * (NPB * 2);
            float4 v = *(const float4*)(x + ((size_t)(b0 + bb) * N_TOT + n0) * IN_DIM + off4 * 4);
            *(float4*)(&sh_x[bb * XR + off4 * 4]) = v;
        }
    }

    // ---- S fragment: all 16 d for (b, c)
    float S[OD];
    if (!FIRST) {
        const float4* sp = (const float4*)(S_acc + (size_t)(b0 + b) * CD + cu * OD);
        #pragma unroll
        for (int q = 0; q < 4; q++) ((float4*)S)[q] = sp[q];
    }

    float acc[OD];
    #pragma unroll
    for (int d = 0; d < OD; d++) acc[d] = 0.f;

    __syncthreads();   // sh_x ready

    const float* Wc = W + cu * OD;    // wave-uniform base

    for (int nn = 0; nn < NPB; nn++) {
        float xf[IN_DIM];
        {
            const float4* xp = (const float4*)(&sh_x[b * XR + nn * IN_DIM]);
            ((float4*)xf)[0] = xp[0];
            ((float4*)xf)[1] = xp[1];
        }

        const float* Wn = Wc + (size_t)(n0 + nn) * (IN_DIM * CD);
        float u[OD];
        #pragma unroll
        for (int d = 0; d < OD; d++) u[d] = xf[0] * Wn[d];
        #pragma unroll
        for (int i = 1; i < IN_DIM; i++) {
            const float* Wi = Wn + i * CD;
            #pragma unroll
            for (int d = 0; d < OD; d++) u[d] = fmaf(xf[i], Wi[d], u[d]);
        }

        if (!FIRST) {
            const int cur = nn & 1;
            float lg = 0.f;
            #pragma unroll
            for (int d = 0; d < OD; d++) lg = fmaf(u[d], S[d], lg);
            sh_lg[cur][cu * LB + b] = lg;
            __syncthreads();

            float m = -1e30f;
            float row[NC];
            #pragma unroll
            for (int k = 0; k < NC; k++) {
                row[k] = sh_lg[cur][k * LB + b];
                m = fmaxf(m, row[k]);
            }
            float den = 0.f;
            #pragma unroll
            for (int k = 0; k < NC; k++) den += __expf(row[k] - m);
            float cw = __expf(lg - m) / den;

            #pragma unroll
            for (int d = 0; d < OD; d++) acc[d] = fmaf(cw, u[d], acc[d]);
        } else {
            #pragma unroll
            for (int d = 0; d < OD; d++) acc[d] += u[d];
        }
    }

    float* dst = part + ((size_t)blockIdx.y * B_TOT + (b0 + b)) * CD + cu * OD;
    #pragma unroll
    for (int q = 0; q < 4; q++)
        ((float4*)dst)[q] = ((float4*)acc)[q];
}

// ===== Merged reduce: one kernel per round, block-scope sync only.
// 40 blocks × 1024 threads; sub-group s (0..3) of each block sums 48 slabs
// for its 256 g-chunk; LDS combine; threads 0..255 apply scale/bias and do
// stage B: store S_acc (round 0 — no memset needed), add (round 1), or
// squash -> v_out (round 2).
__global__ __launch_bounds__(1024) void reduce_round(
    const float* __restrict__ part,   // [NS, B, 160]
    float* __restrict__ S_acc,        // [B, 160]
    float* __restrict__ v_out,        // [B, 10, 16]
    float scale, int round)
{
    __shared__ float4 sh[RSUB][256];  // 16 KB

    const int gl  = threadIdx.x & 255;
    const int sub = threadIdx.x >> 8;        // 0..3
    const int g   = blockIdx.x * 256 + gl;   // float4 index in [B*160/4)

    const float4* p4 = (const float4*)part + (size_t)sub * YSUB * NF4 + g;
    float4 s = { 0.f, 0.f, 0.f, 0.f };
    #pragma unroll 4
    for (int y = 0; y < YSUB; y++) {
        float4 t = p4[(size_t)y * NF4];
        s.x += t.x; s.y += t.y; s.z += t.z; s.w += t.w;
    }
    sh[sub][gl] = s;
    __syncthreads();

    if (threadIdx.x < 256) {
        float4 a = sh[0][gl], b = sh[1][gl], c = sh[2][gl], d = sh[3][gl];
        float4 t = { a.x + b.x + c.x + d.x,
                     a.y + b.y + c.y + d.y,
                     a.z + b.z + c.z + d.z,
                     a.w + b.w + c.w + d.w };
        t.x = t.x * scale + RBIAS;
        t.y = t.y * scale + RBIAS;
        t.z = t.z * scale + RBIAS;
        t.w = t.w * scale + RBIAS;

        if (round == 0) {
            ((float4*)S_acc)[g] = t;          // store — no memset required
        } else if (round == 1) {
            float4 o = ((float4*)S_acc)[g];
            o.x += t.x; o.y += t.y; o.z += t.z; o.w += t.w;
            ((float4*)S_acc)[g] = o;
        } else {
            // squash: 16 d = 4 consecutive g = lanes 4k..4k+3 of this wave
            float ss = t.x * t.x + t.y * t.y + t.z * t.z + t.w * t.w;
            ss += __shfl_xor(ss, 1, 64);
            ss += __shfl_xor(ss, 2, 64);
            float norm = sqrtf(ss);
            float k2 = norm / (1.0f + ss);
            float4 v = { t.x * k2, t.y * k2, t.z * k2, t.w * k2 };
            ((float4*)v_out)[g] = v;
        }
    }
}

extern "C" void kernel_launch(void* const* d_in, const int* in_sizes, int n_in,
                              void* d_out, int out_size, void* d_ws, size_t ws_size,
                              hipStream_t stream) {
    const float* x = (const float*)d_in[0];   // [256,2304,8]
    const float* W = (const float*)d_in[1];   // [2304,8,160]
    float* out = (float*)d_out;               // [256,10,16]

    // Workspace (every byte written before read each call — re-poison safe)
    float* part  = (float*)d_ws;                            // NS * 40960  (~31.5 MB)
    float* S_acc = part + (size_t)NS * B_TOT * CD;          // 40960 floats

    const dim3 rgrid(B_TOT / BTILE, NS);
    const int  RG = NF4 / 256;   // 40

    // Round 0 (uniform cw; 0.1 folded into reduce scale; S_acc stored not added)
    routing_round<1><<<rgrid, NTHREADS, 0, stream>>>(x, W, S_acc, part);
    reduce_round<<<RG, 1024, 0, stream>>>(part, S_acc, out, 0.1f, 0);

    // Round 1
    routing_round<0><<<rgrid, NTHREADS, 0, stream>>>(x, W, S_acc, part);
    reduce_round<<<RG, 1024, 0, stream>>>(part, S_acc, out, 1.0f, 1);

    // Round 2 (+final squash fused)
    routing_round<0><<<rgrid, NTHREADS, 0, stream>>>(x, W, S_acc, part);
    reduce_round<<<RG, 1024, 0, stream>>>(part, S_acc, out, 1.0f, 2);
}

// Round 12
// 212.391 us; speedup vs baseline: 1.5286x; 1.0557x over previous
//
#include <hip/hip_runtime.h>
#include <math.h>

// Problem constants (fixed by reference)
#define B_TOT   256
#define N_TOT   2304
#define IN_DIM  8
#define NC      10      // NUM_CLASSES
#define OD      16      // OUT_DIM
#define CD      160     // NC*OD
#define RBIAS   0.1f

// Tiling: wave-per-class layout. Block = 10 waves (c=0..9) × 64 lanes (b).
#define BTILE    64                      // b per block (= wave lanes)
#define NS       192                     // n-slices (grid.y); grid = 4*192 = 768 = 3 blk/CU
#define NPB      (N_TOT / NS)            // 12 n per block
#define NTHREADS 640                     // 10 waves
#define XR       (NPB * IN_DIM + 4)      // 100: x row stride
#define LB       72                      // logit board row stride
#define NF4      (B_TOT * CD / 4)        // 10240 float4 per partial slab
#define RCOLS    32                      // float4-columns per reduce block
#define RGRPS    8                       // y-groups per reduce block
#define RYPER    (NS / RGRPS)            // 24 slabs per (col, grp) thread

// ===== R7's proven routing round (51.2us, VGPR=32, 0 bank conflicts) — UNCHANGED =====
// Wave c, lane b. Thread owns u[16] for (b0+b, class c). W[n,i,c*16..+16) is
// wave-uniform -> scalar loads (SGPR operand); W never touches LDS/VGPRs.
// FIRST=1: cw uniform -> acc += u, no logits/barriers; 0.1 folded in reduce.
template <int FIRST>
__global__ __launch_bounds__(NTHREADS) void routing_round(
    const float* __restrict__ x,      // [B, N, 8]
    const float* __restrict__ W,      // [N, 8, 160]
    const float* __restrict__ S_acc,  // [B, 160]
    float* __restrict__ part)         // [NS, B, 160]
{
    __shared__ float sh_x[BTILE * XR];            // 25.6 KB
    __shared__ float sh_lg[2][NC * LB];           // 5.8 KB

    const int tid = threadIdx.x;
    const int b0  = blockIdx.x * BTILE;
    const int n0  = blockIdx.y * NPB;
    const int b   = tid & 63;
    const int cu  = __builtin_amdgcn_readfirstlane(tid >> 6);

    // ---- stage x tile: [64 b][96 floats], coalesced float4
    {
        const int XT4 = BTILE * (NPB * IN_DIM / 4);   // 1536
        for (int k = tid; k < XT4; k += NTHREADS) {
            int bb   = k / (NPB * 2);
            int off4 = k - bb * (NPB * 2);
            float4 v = *(const float4*)(x + ((size_t)(b0 + bb) * N_TOT + n0) * IN_DIM + off4 * 4);
            *(float4*)(&sh_x[bb * XR + off4 * 4]) = v;
        }
    }

    // ---- S fragment: all 16 d for (b, c)
    float S[OD];
    if (!FIRST) {
        const float4* sp = (const float4*)(S_acc + (size_t)(b0 + b) * CD + cu * OD);
        #pragma unroll
        for (int q = 0; q < 4; q++) ((float4*)S)[q] = sp[q];
    }

    float acc[OD];
    #pragma unroll
    for (int d = 0; d < OD; d++) acc[d] = 0.f;

    __syncthreads();   // sh_x ready

    const float* Wc = W + cu * OD;    // wave-uniform base

    for (int nn = 0; nn < NPB; nn++) {
        float xf[IN_DIM];
        {
            const float4* xp = (const float4*)(&sh_x[b * XR + nn * IN_DIM]);
            ((float4*)xf)[0] = xp[0];
            ((float4*)xf)[1] = xp[1];
        }

        const float* Wn = Wc + (size_t)(n0 + nn) * (IN_DIM * CD);
        float u[OD];
        #pragma unroll
        for (int d = 0; d < OD; d++) u[d] = xf[0] * Wn[d];
        #pragma unroll
        for (int i = 1; i < IN_DIM; i++) {
            const float* Wi = Wn + i * CD;
            #pragma unroll
            for (int d = 0; d < OD; d++) u[d] = fmaf(xf[i], Wi[d], u[d]);
        }

        if (!FIRST) {
            const int cur = nn & 1;
            float lg = 0.f;
            #pragma unroll
            for (int d = 0; d < OD; d++) lg = fmaf(u[d], S[d], lg);
            sh_lg[cur][cu * LB + b] = lg;
            __syncthreads();

            float m = -1e30f;
            float row[NC];
            #pragma unroll
            for (int k = 0; k < NC; k++) {
                row[k] = sh_lg[cur][k * LB + b];
                m = fmaxf(m, row[k]);
            }
            float den = 0.f;
            #pragma unroll
            for (int k = 0; k < NC; k++) den += __expf(row[k] - m);
            float cw = __expf(lg - m) / den;

            #pragma unroll
            for (int d = 0; d < OD; d++) acc[d] = fmaf(cw, u[d], acc[d]);
        } else {
            #pragma unroll
            for (int d = 0; d < OD; d++) acc[d] += u[d];
        }
    }

    float* dst = part + ((size_t)blockIdx.y * B_TOT + (b0 + b)) * CD + cu * OD;
    #pragma unroll
    for (int q = 0; q < 4; q++)
        ((float4*)dst)[q] = ((float4*)acc)[q];
}

// ===== Full-device merged reduce: 320 blocks × 256 threads (spans all CUs —
// R11 post-mortem: 40-block reduce ran at 1/6 device BW, ~25us). Block owns
// 32 float4-columns; thread (col, grp) sums 24 slabs (y = grp + 8k); LDS
// combine (block-scope only); threads 0..31 apply scale/bias + stage B:
// store S_acc (round 0 — no memset), add (round 1), squash -> v_out (round 2).
__global__ __launch_bounds__(256) void reduce_round(
    const float* __restrict__ part,   // [NS, B, 160]
    float* __restrict__ S_acc,        // [B, 160]
    float* __restrict__ v_out,        // [B, 10, 16]
    float scale, int round)
{
    __shared__ float4 sh[RGRPS][RCOLS];   // 4 KB

    const int col = threadIdx.x & (RCOLS - 1);
    const int grp = threadIdx.x >> 5;               // 0..7
    const int g   = blockIdx.x * RCOLS + col;       // float4 column index

    const float4* p4 = (const float4*)part + (size_t)grp * NF4 + g;
    float4 s = { 0.f, 0.f, 0.f, 0.f };
    #pragma unroll 4
    for (int y = 0; y < RYPER; y++) {               // slabs grp, grp+8, ...
        float4 t = p4[(size_t)y * RGRPS * NF4];
        s.x += t.x; s.y += t.y; s.z += t.z; s.w += t.w;
    }
    sh[grp][col] = s;
    __syncthreads();

    if (threadIdx.x < RCOLS) {
        float4 t = { 0.f, 0.f, 0.f, 0.f };
        #pragma unroll
        for (int k = 0; k < RGRPS; k++) {
            float4 q = sh[k][col];
            t.x += q.x; t.y += q.y; t.z += q.z; t.w += q.w;
        }
        t.x = t.x * scale + RBIAS;
        t.y = t.y * scale + RBIAS;
        t.z = t.z * scale + RBIAS;
        t.w = t.w * scale + RBIAS;

        if (round == 0) {
            ((float4*)S_acc)[g] = t;          // store — no memset required
        } else if (round == 1) {
            float4 o = ((float4*)S_acc)[g];
            o.x += t.x; o.y += t.y; o.z += t.z; o.w += t.w;
            ((float4*)S_acc)[g] = o;
        } else {
            // squash: 16 d = 4 consecutive float4 columns = lanes 4k..4k+3
            float ss = t.x * t.x + t.y * t.y + t.z * t.z + t.w * t.w;
            ss += __shfl_xor(ss, 1, 64);
            ss += __shfl_xor(ss, 2, 64);
            float norm = sqrtf(ss);
            float k2 = norm / (1.0f + ss);
            float4 v = { t.x * k2, t.y * k2, t.z * k2, t.w * k2 };
            ((float4*)v_out)[g] = v;
        }
    }
}

extern "C" void kernel_launch(void* const* d_in, const int* in_sizes, int n_in,
                              void* d_out, int out_size, void* d_ws, size_t ws_size,
                              hipStream_t stream) {
    const float* x = (const float*)d_in[0];   // [256,2304,8]
    const float* W = (const float*)d_in[1];   // [2304,8,160]
    float* out = (float*)d_out;               // [256,10,16]

    // Workspace (every byte written before read each call — re-poison safe)
    float* part  = (float*)d_ws;                            // NS * 40960  (~31.5 MB)
    float* S_acc = part + (size_t)NS * B_TOT * CD;          // 40960 floats

    const dim3 rgrid(B_TOT / BTILE, NS);
    const int  RG = NF4 / RCOLS;   // 320 reduce blocks — spans the device

    // Round 0 (uniform cw; 0.1 folded into reduce scale; S_acc stored not added)
    routing_round<1><<<rgrid, NTHREADS, 0, stream>>>(x, W, S_acc, part);
    reduce_round<<<RG, 256, 0, stream>>>(part, S_acc, out, 0.1f, 0);

    // Round 1
    routing_round<0><<<rgrid, NTHREADS, 0, stream>>>(x, W, S_acc, part);
    reduce_round<<<RG, 256, 0, stream>>>(part, S_acc, out, 1.0f, 1);

    // Round 2 (+final squash fused)
    routing_round<0><<<rgrid, NTHREADS, 0, stream>>>(x, W, S_acc, part);
    reduce_round<<<RG, 256, 0, stream>>>(part, S_acc, out, 1.0f, 2);
}